// Round 10
// baseline (4357.556 us; speedup 1.0000x reference)
//
#include <hip/hip_runtime.h>
#include <hip/hip_fp16.h>

#define NN 100000
#define NE 1600000
#define HD 128
#define HD2 256

// binned scatter params
#define NBK 512
#define RPB 196      // rows per bucket; 512*196 = 100352 >= NN
#define CH  4096     // edges per binscatter block
#define CAP 4096     // staging capacity per bucket (17-sigma above mean 3136)

typedef unsigned int u32;
typedef unsigned short u16;
typedef _Float16 half8 __attribute__((ext_vector_type(8)));
typedef float floatx4 __attribute__((ext_vector_type(4)));

static inline int cdiv(int a, int b){ return (a + b - 1) / b; }

// ---- split-fp16 packing: x ~= h + l * 2^-12, l pre-scaled by 4096 ----
__device__ __forceinline__ u32 split_pack(float v){
  __half h;
  if(fabsf(v) < 6.103515625e-05f) h = __ushort_as_half((u16)0);
  else h = __float2half_rn(v);
  float hf = __half2float(h);
  __half l = __float2half_rn((v - hf) * 4096.0f);
  return (u32)__half_as_ushort(h) | ((u32)__half_as_ushort(l) << 16);
}

// ---------------- fused setup: weights -> fragment-ordered BF planes + sc zero + bcur ----
// BF layout per weight (K,N), planes u16[K*N]:
//   e = ((nfrag*(K/32) + ks)*64 + lane)*8 + j  ->  element (k = ks*32+(lane>>4)*8+j,
//   c = nfrag*16+(lane&15)) of W^T; a wave's fragment load is 1KB contiguous.
// Regions (u16 elems): w_i at i*16384, m1 at 131072, m2 at 163840; total 229376.
__global__ void k_setup(const float* __restrict__ w0, const float* __restrict__ w1,
                        const float* __restrict__ w2, const float* __restrict__ w3,
                        const float* __restrict__ w4, const float* __restrict__ w5,
                        const float* __restrict__ w6, const float* __restrict__ w7,
                        const float* __restrict__ m1, const float* __restrict__ m2,
                        u16* __restrict__ bfh, u16* __restrict__ bfl,
                        float* __restrict__ sc, int* __restrict__ bcur){
  int bid = blockIdx.x;
  if(bid < 896){
    int idx = bid * 256 + threadIdx.x;      // 896*256 = 229376 exact
    const float* W; int K, N, e;
    if(idx < 131072){
      int wi = idx >> 14; e = idx & 16383; K = HD; N = HD;
      W = wi == 0 ? w0 : wi == 1 ? w1 : wi == 2 ? w2 : wi == 3 ? w3 :
          wi == 4 ? w4 : wi == 5 ? w5 : wi == 6 ? w6 : w7;
    } else if(idx < 163840){
      e = idx - 131072; K = HD; N = HD2; W = m1;
    } else {
      e = idx - 163840; K = HD2; N = HD2; W = m2;
    }
    int KS = K >> 5;
    int j = e & 7, lane = (e >> 3) & 63, rest = e >> 9;
    int ks = rest % KS, nfrag = rest / KS;
    int c = nfrag * 16 + (lane & 15);
    int k = ks * 32 + (lane >> 4) * 8 + j;
    u32 p = split_pack(W[(size_t)k * N + c]);
    bfh[idx] = (u16)(p & 0xffffu);
    bfl[idx] = (u16)(p >> 16);
  } else if(bid < 896 + 782){
    int i = (bid - 896) * 256 + threadIdx.x;
    if(i < 2 * NN) sc[i] = 0.f;
  } else {
    int i = (bid - 896 - 782) * 256 + threadIdx.x;
    if(i < 2 * NBK) bcur[i] = (i & (NBK - 1)) * CAP;
  }
}

// pass B: LDS-binned scatter into fixed-capacity bucket staging (burst writes)
__global__ void k_binscatter(const int* __restrict__ r0a, const int* __restrict__ c0a,
                             const float* __restrict__ v0a,
                             const int* __restrict__ r1a, const int* __restrict__ c1a,
                             const float* __restrict__ v1a,
                             int* __restrict__ bcur,
                             u32* __restrict__ sr0, uint2* __restrict__ sv0,
                             u32* __restrict__ sr1, uint2* __restrict__ sv1){
  __shared__ int cnt[NBK];
  __shared__ int bstart[NBK];
  __shared__ int gbase[NBK];
  __shared__ int sh[256];
  __shared__ u32 srow[CH];
  __shared__ uint2 scvs[CH];
  int z = blockIdx.y;
  const int* rows = z ? r1a : r0a;
  const int* cols = z ? c1a : c0a;
  const float* vals = z ? v1a : v0a;
  int* cur = bcur + z * NBK;
  u32* osr = z ? sr1 : sr0;
  uint2* osv = z ? sv1 : sv0;
  int t = threadIdx.x;
  for(int i = t; i < NBK; i += 256) cnt[i] = 0;
  __syncthreads();
  int e0 = blockIdx.x * CH;
  int total = NE - e0; if(total > CH) total = CH;
  int r_[16], c_[16], b_[16], k_[16]; float v_[16];
  #pragma unroll
  for(int k = 0; k < 16; k++){
    int e = e0 + t + k * 256;
    b_[k] = -1;
    if(e < NE){
      r_[k] = rows[e]; c_[k] = cols[e]; v_[k] = vals[e];
      b_[k] = r_[k] / RPB;
      k_[k] = atomicAdd(&cnt[b_[k]], 1);
    }
  }
  __syncthreads();
  // exclusive scan of cnt[512] with 256 threads (2 elems/thread)
  int v0 = cnt[2 * t], v1 = cnt[2 * t + 1];
  int s2 = v0 + v1;
  sh[t] = s2;
  __syncthreads();
  for(int d = 1; d < 256; d <<= 1){
    int tv = (t >= d) ? sh[t - d] : 0;
    __syncthreads();
    sh[t] += tv;
    __syncthreads();
  }
  int excl = sh[t] - s2;
  bstart[2 * t] = excl;
  bstart[2 * t + 1] = excl + v0;
  __syncthreads();
  // stage into LDS sorted-by-bucket
  #pragma unroll
  for(int k = 0; k < 16; k++){
    if(b_[k] >= 0){
      int slot = bstart[b_[k]] + k_[k];
      srow[slot] = (u32)r_[k];
      scvs[slot] = make_uint2((u32)c_[k], __float_as_uint(v_[k]));
    }
  }
  // reserve staging space per bucket (one atomic per non-empty bucket)
  for(int b = t; b < NBK; b += 256){
    int c = cnt[b];
    if(c > 0) gbase[b] = atomicAdd(&cur[b], c);
  }
  __syncthreads();
  // burst write-out: consecutive i -> same bucket -> contiguous dest
  for(int i = t; i < total; i += 256){
    u32 r = srow[i];
    int b = (int)r / RPB;
    int dest = gbase[b] + (i - bstart[b]);
    osr[dest] = r;
    osv[dest] = scvs[i];
  }
}

// bucket totals -> global bucket bases (exclusive scan over 512), + rowptr[NN]=NE
__global__ void k_bucket_scan(const int* __restrict__ bcur, int* __restrict__ bbase,
                              int* __restrict__ c1ptr, int* __restrict__ c2ptr){
  __shared__ int sh[256];
  int z = blockIdx.x;
  const int* cur = bcur + z * NBK;
  int* bb = bbase + z * NBK;
  int t = threadIdx.x;
  int v0 = cur[2 * t]     - (2 * t) * CAP;
  int v1 = cur[2 * t + 1] - (2 * t + 1) * CAP;
  int s2 = v0 + v1;
  sh[t] = s2;
  __syncthreads();
  for(int d = 1; d < 256; d <<= 1){
    int tv = (t >= d) ? sh[t - d] : 0;
    __syncthreads();
    sh[t] += tv;
    __syncthreads();
  }
  int excl = sh[t] - s2;
  bb[2 * t] = excl;
  bb[2 * t + 1] = excl + v0;
  if(t == 0){
    int* rp = z ? c2ptr : c1ptr;
    rp[NN] = NE;
  }
}

// pass C: per-bucket — LDS row-histogram + local scan -> rowptr, then CSR placement
__global__ void k_bucket_place(const int* __restrict__ bcur, const int* __restrict__ bbase,
                               const u32* __restrict__ sr0, const uint2* __restrict__ sv0,
                               const u32* __restrict__ sr1, const uint2* __restrict__ sv1,
                               int* __restrict__ c1ptr, int* __restrict__ c2ptr,
                               uint2* __restrict__ e0, uint2* __restrict__ e1){
  __shared__ int hist[RPB];
  __shared__ int cur[RPB];
  __shared__ int sh[256];
  __shared__ u32 srows[CAP];
  int z = blockIdx.y;
  int b = blockIdx.x;
  int r0 = b * RPB;
  if(r0 >= NN) return;
  int rend = r0 + RPB; if(rend > NN) rend = NN;
  int nr = rend - r0;
  const u32* sr = z ? sr1 : sr0;
  const uint2* sv = z ? sv1 : sv0;
  int* rp = z ? c2ptr : c1ptr;
  uint2* ecv = z ? e1 : e0;
  int cnt = bcur[z * NBK + b] - b * CAP;
  int base = bbase[z * NBK + b];
  int g = b * CAP;
  int t = threadIdx.x;
  for(int r = t; r < nr; r += 256) hist[r] = 0;
  __syncthreads();
  for(int i = t; i < cnt; i += 256){
    u32 r = sr[g + i];
    srows[i] = r;
    atomicAdd(&hist[(int)r - r0], 1);
  }
  __syncthreads();
  int v = (t < nr) ? hist[t] : 0;
  sh[t] = v;
  __syncthreads();
  for(int d = 1; d < 256; d <<= 1){
    int tv = (t >= d) ? sh[t - d] : 0;
    __syncthreads();
    sh[t] += tv;
    __syncthreads();
  }
  int excl = sh[t] - v;
  if(t < nr){
    rp[r0 + t] = base + excl;
    cur[t] = base + excl;
  }
  __syncthreads();
  for(int i = t; i < cnt; i += 256){
    int r = (int)srows[i] - r0;
    int p = atomicAdd(&cur[r], 1);
    ecv[p] = sv[g + i];
  }
}

// ---------------- SpMM: one wave per node; 2 edges/step via half-waves, float4 gather ----
template<bool NORM>
__global__ void k_spmm(const int* __restrict__ rowptr, const uint2* __restrict__ ecv,
                       const float* __restrict__ X, u32* __restrict__ outpk){
  int node = (blockIdx.x << 2) + (threadIdx.x >> 6);
  int lane = threadIdx.x & 63;
  if(node >= NN) return;
  int h = lane >> 5, s = lane & 31;
  int sb = rowptr[node], e = rowptr[node + 1];
  float ax = 0.f, ay = 0.f, az = 0.f, aw = 0.f;
  int i = sb;
  for(; i + 7 < e; i += 8){
    uint2 ee[4]; float4 xx[4];
    #pragma unroll
    for(int j = 0; j < 4; j++) ee[j] = ecv[i + 2 * j + h];
    #pragma unroll
    for(int j = 0; j < 4; j++) xx[j] = *(const float4*)(X + (size_t)ee[j].x * HD + s * 4);
    #pragma unroll
    for(int j = 0; j < 4; j++){
      float vv = __uint_as_float(ee[j].y);
      ax = fmaf(vv, xx[j].x, ax);
      ay = fmaf(vv, xx[j].y, ay);
      az = fmaf(vv, xx[j].z, az);
      aw = fmaf(vv, xx[j].w, aw);
    }
  }
  for(; i < e; i += 2){
    int idx = i + h;
    bool ok = idx < e;
    uint2 f = ecv[ok ? idx : i];
    float vv = ok ? __uint_as_float(f.y) : 0.f;
    float4 xv = *(const float4*)(X + (size_t)f.x * HD + s * 4);
    ax = fmaf(vv, xv.x, ax);
    ay = fmaf(vv, xv.y, ay);
    az = fmaf(vv, xv.z, az);
    aw = fmaf(vv, xv.w, aw);
  }
  ax += __shfl_xor(ax, 32, 64);
  ay += __shfl_xor(ay, 32, 64);
  az += __shfl_xor(az, 32, 64);
  aw += __shfl_xor(aw, 32, 64);
  ax = fmaxf(ax, 0.f); ay = fmaxf(ay, 0.f);
  az = fmaxf(az, 0.f); aw = fmaxf(aw, 0.f);
  if(NORM){
    float ss = ax * ax + ay * ay + az * az + aw * aw;
    #pragma unroll
    for(int o = 16; o >= 1; o >>= 1) ss += __shfl_xor(ss, o, 64);
    float scale = 1.f / fmaxf(sqrtf(ss), 1e-12f);
    ax *= scale; ay *= scale; az *= scale; aw *= scale;
  }
  if(h == 0){
    uint4 p;
    p.x = split_pack(ax); p.y = split_pack(ay);
    p.z = split_pack(az); p.w = split_pack(aw);
    *(uint4*)(outpk + (size_t)node * HD + s * 4) = p;
  }
}

// ---------------- split-fp16 MFMA GEMM: A via LDS (proven), B via fragment-ordered ----
// global reads (wave-coalesced 1KB, L2-hot weights) — no B staging, no B unpack.
// XCD-paired col-tiles as before.
// MODE 0: Yout = A@B (fp32). MODE 1: Hout = pack(relu(A@B+bias)).
// MODE 2: score[m] += sum_n relu(A@B+bias)[m][n]*m3[n].
// MODE 3: fused — ct==0: B=w_i -> Yout [M][HD]; ct in {1,2}: B=m1 -> Hout [M][HD2].
template<int MODE>
__launch_bounds__(256, 2)
__global__ void k_mfma_gemm(const u32* __restrict__ Apk,
                            const u16* __restrict__ BGh, const u16* __restrict__ BGl,
                            const u16* __restrict__ B1Gh, const u16* __restrict__ B1Gl,
                            const float* __restrict__ bias, float* __restrict__ Yout,
                            u32* __restrict__ Hout, const float* __restrict__ m3,
                            float* __restrict__ score, int M, int K, int N){
  __shared__ u16 As_h[128 * 40], As_l[128 * 40];
  constexpr int NYC = (MODE == 0) ? 1 : ((MODE == 3) ? 3 : 2);
  const int d = blockIdx.x;
  const int grp = d / (8 * NYC);
  const int rem = d - grp * 8 * NYC;
  const int rt = grp * 8 + (rem & 7);
  const int ct = rem >> 3;
  const int nrt = (M + 127) >> 7;
  if(rt >= nrt) return;
  const int tid = threadIdx.x;
  const int lane = tid & 63, wid = tid >> 6;
  const int lm = lane & 15, lg = lane >> 4;
  const int mq = (wid & 1) * 64, nq = (wid >> 1) * 64;
  const int m0 = rt * 128;
  int n0 = ct * 128;
  const u16* Bh = BGh; const u16* Bl = BGl;
  bool m0path = true;
  if(MODE == 3){
    m0path = (ct == 0);
    if(m0path){ n0 = 0; }
    else      { n0 = (ct - 1) * 128; Bh = B1Gh; Bl = B1Gl; }
  }
  const int KS = K >> 5;
  const int nf0 = (n0 + nq) >> 4;

  floatx4 accA[4][4], accB[4][4];
  #pragma unroll
  for(int i = 0; i < 4; i++)
    #pragma unroll
    for(int j = 0; j < 4; j++){
      accA[i][j] = (floatx4){0.f, 0.f, 0.f, 0.f};
      accB[i][j] = (floatx4){0.f, 0.f, 0.f, 0.f};
    }

  for(int k0 = 0, ks = 0; k0 < K; k0 += 32, ks++){
    uint4 av[4];
    #pragma unroll
    for(int j = 0; j < 4; j++){
      int li = tid + j * 256;
      int row = li >> 3, kc = (li & 7) * 4;
      int ar = m0 + row; if(ar >= M) ar = M - 1;
      av[j] = *(const uint4*)(Apk + (size_t)ar * K + k0 + kc);
    }
    if(k0) __syncthreads();
    #pragma unroll
    for(int j = 0; j < 4; j++){
      int li = tid + j * 256;
      int row = li >> 3, kc = (li & 7) * 4;
      int base = row * 40 + kc;
      ushort4 h, l;
      h.x = (u16)(av[j].x & 0xffff); l.x = (u16)(av[j].x >> 16);
      h.y = (u16)(av[j].y & 0xffff); l.y = (u16)(av[j].y >> 16);
      h.z = (u16)(av[j].z & 0xffff); l.z = (u16)(av[j].z >> 16);
      h.w = (u16)(av[j].w & 0xffff); l.w = (u16)(av[j].w >> 16);
      *(ushort4*)&As_h[base] = h;
      *(ushort4*)&As_l[base] = l;
    }
    __syncthreads();

    half8 fa_h[4], fa_l[4], fb_h[4], fb_l[4];
    // B fragments direct from fragment-ordered global (1KB coalesced per wave-load)
    {
      size_t bo = (((size_t)nf0 * KS + ks) << 9) + lane * 8;
      #pragma unroll
      for(int s = 0; s < 4; s++){
        fb_h[s] = *(const half8*)(Bh + bo + (((size_t)s * KS) << 9));
        fb_l[s] = *(const half8*)(Bl + bo + (((size_t)s * KS) << 9));
      }
    }
    #pragma unroll
    for(int s = 0; s < 4; s++){
      int ra = (mq + s * 16 + lm) * 40 + lg * 8;
      fa_h[s] = *(const half8*)&As_h[ra];
      fa_l[s] = *(const half8*)&As_l[ra];
    }
    #pragma unroll
    for(int i = 0; i < 4; i++)
      #pragma unroll
      for(int j = 0; j < 4; j++){
        accA[i][j] = __builtin_amdgcn_mfma_f32_16x16x32_f16(fa_h[i], fb_h[j], accA[i][j], 0, 0, 0);
        accB[i][j] = __builtin_amdgcn_mfma_f32_16x16x32_f16(fa_h[i], fb_l[j], accB[i][j], 0, 0, 0);
        accB[i][j] = __builtin_amdgcn_mfma_f32_16x16x32_f16(fa_l[i], fb_h[j], accB[i][j], 0, 0, 0);
      }
  }

  const float inv4096 = 1.f / 4096.f;
  if(MODE == 0 || (MODE == 3 && m0path)){
    int ldy = (MODE == 3) ? HD : N;
    #pragma unroll
    for(int i = 0; i < 4; i++)
      #pragma unroll
      for(int r = 0; r < 4; r++){
        int m = m0 + mq + i * 16 + lg * 4 + r;
        if(m < M){
          #pragma unroll
          for(int j = 0; j < 4; j++){
            int c = n0 + nq + j * 16 + lm;
            Yout[(size_t)m * ldy + c] = accA[i][j][r] + accB[i][j][r] * inv4096;
          }
        }
      }
  } else if(MODE == 1 || MODE == 3){
    int ldh = (MODE == 3) ? HD2 : N;
    #pragma unroll
    for(int i = 0; i < 4; i++)
      #pragma unroll
      for(int r = 0; r < 4; r++){
        int m = m0 + mq + i * 16 + lg * 4 + r;
        if(m < M){
          #pragma unroll
          for(int j = 0; j < 4; j++){
            int c = n0 + nq + j * 16 + lm;
            float v = fmaxf(accA[i][j][r] + accB[i][j][r] * inv4096 + bias[c], 0.f);
            Hout[(size_t)m * ldh + c] = split_pack(v);
          }
        }
      }
  } else {
    #pragma unroll
    for(int i = 0; i < 4; i++)
      #pragma unroll
      for(int r = 0; r < 4; r++){
        float s = 0.f;
        #pragma unroll
        for(int j = 0; j < 4; j++){
          int c = n0 + nq + j * 16 + lm;
          float v = fmaxf(accA[i][j][r] + accB[i][j][r] * inv4096 + bias[c], 0.f);
          s = fmaf(v, m3[c], s);
        }
        s += __shfl_xor(s, 1, 64);
        s += __shfl_xor(s, 2, 64);
        s += __shfl_xor(s, 4, 64);
        s += __shfl_xor(s, 8, 64);
        int m = m0 + mq + i * 16 + lg * 4 + r;
        if(lm == 0 && m < M) atomicAdd(&score[m], s);
      }
  }
}

__global__ void k_final(const float* __restrict__ sc, const float* __restrict__ b3,
                        float* __restrict__ out){
  int i = blockIdx.x * 256 + threadIdx.x;
  if(i < NN){
    float b = 9.f * b3[0];
    out[i] = (sc[i] + b) * (sc[NN + i] + b);
  }
}

// ---------------- launcher ----------------
extern "C" void kernel_launch(void* const* d_in, const int* in_sizes, int n_in,
                              void* d_out, int out_size, void* d_ws, size_t ws_size,
                              hipStream_t stream){
  const int*   a1r = (const int*)d_in[0];
  const int*   a1c = (const int*)d_in[1];
  const float* a1v = (const float*)d_in[2];
  const int*   a2r = (const int*)d_in[3];
  const int*   a2c = (const int*)d_in[4];
  const float* a2v = (const float*)d_in[5];
  const float* w1  = (const float*)d_in[6];
  const float* w[8];
  for(int i = 0; i < 8; i++) w[i] = (const float*)d_in[7 + i];
  const float* m1 = (const float*)d_in[15];
  const float* b1 = (const float*)d_in[16];
  const float* m2 = (const float*)d_in[17];
  const float* b2 = (const float*)d_in[18];
  const float* m3 = (const float*)d_in[19];
  const float* b3 = (const float*)d_in[20];
  float* out = (float*)d_out;

  char* base = (char*)d_ws;
  size_t off = 0;
  auto alloc = [&](size_t bytes) -> char* {
    char* r = base + off;
    off += (bytes + 255) & ~(size_t)255;
    return r;
  };
  int*   c1ptr = (int*)  alloc((size_t)(NN + 1) * 4);
  int*   c2ptr = (int*)  alloc((size_t)(NN + 1) * 4);
  uint2* ecv1  = (uint2*)alloc((size_t)NE * 8);
  uint2* ecv2  = (uint2*)alloc((size_t)NE * 8);
  int*   cursor= (int*)  alloc((size_t)2 * NBK * 4);
  int*   bbase = (int*)  alloc((size_t)2 * NBK * 4);
  float* sc    = (float*)alloc((size_t)2 * NN * 4);
  u16*   bfh   = (u16*)  alloc((size_t)229376 * 2);
  u16*   bfl   = (u16*)  alloc((size_t)229376 * 2);
  u32*   xpk   = (u32*)alloc((size_t)NN * HD * 4);
  u32*   h1pk  = (u32*)alloc((size_t)NN * HD2 * 4);
  // fused01 tier needs dedicated y (fp32 [NN][HD]); else alias h1pk and run r6 schedule
  size_t need_ded = off + (((size_t)NN * HD * 4 + 255) & ~(size_t)255);
  bool ded_y = (ws_size >= need_ded);
  float* y = ded_y ? (float*)alloc((size_t)NN * HD * 4) : (float*)h1pk;

  // BF regions (u16 elems): w_i at i*16384, m1 at 131072, m2 at 163840
  const u16* m1h = bfh + 131072; const u16* m1l = bfl + 131072;
  const u16* m2h = bfh + 163840; const u16* m2l = bfl + 163840;

  // binned-scatter staging aliases h1pk (dead during CSR build): 50.3MB < 102.4MB
  const size_t SZ = (size_t)NBK * CAP;
  char* hb = (char*)h1pk;
  uint2* sv1 = (uint2*)hb;
  u32*   sr1 = (u32*)(hb + SZ * 8);
  uint2* sv2 = (uint2*)(hb + SZ * 12);
  u32*   sr2 = (u32*)(hb + SZ * 20);

  // ---- fused setup (BF weight format + sc zero + bucket cursor init), then CSR build ----
  hipLaunchKernelGGL(k_setup, dim3(896 + 782 + 4), dim3(256), 0, stream,
                     w[0], w[1], w[2], w[3], w[4], w[5], w[6], w[7], m1, m2,
                     bfh, bfl, sc, cursor);
  hipLaunchKernelGGL(k_binscatter, dim3(cdiv(NE, CH), 2), dim3(256), 0, stream,
                     a1r, a1c, a1v, a2r, a2c, a2v, cursor, sr1, sv1, sr2, sv2);
  hipLaunchKernelGGL(k_bucket_scan, dim3(2), dim3(256), 0, stream, cursor, bbase, c1ptr, c2ptr);
  hipLaunchKernelGGL(k_bucket_place, dim3(NBK, 2), dim3(256), 0, stream,
                     cursor, bbase, sr1, sv1, sr2, sv2, c1ptr, c2ptr, ecv1, ecv2);

  const int NRT = cdiv(NN, 128);          // 782 row tiles
  const int GP  = cdiv(NRT, 8) * 8;       // 784 padded rows
  const int SPB = cdiv(NN, 4);            // 25000 spmm blocks
  auto mode1 = [&](){
    hipLaunchKernelGGL((k_mfma_gemm<1>), dim3(GP * 2), dim3(256), 0, stream,
                       xpk, m1h, m1l, (const u16*)nullptr, (const u16*)nullptr,
                       b1, (float*)nullptr, h1pk,
                       (const float*)nullptr, (float*)nullptr, NN, HD, HD2);
  };
  auto mode2 = [&](float* score){
    hipLaunchKernelGGL((k_mfma_gemm<2>), dim3(GP * 2), dim3(256), 0, stream,
                       h1pk, m2h, m2l, (const u16*)nullptr, (const u16*)nullptr,
                       b2, (float*)nullptr, (u32*)nullptr,
                       m3, score, NN, HD2, HD2);
  };
  auto gemm0 = [&](int i){
    hipLaunchKernelGGL((k_mfma_gemm<0>), dim3(GP * 1), dim3(256), 0, stream,
                       xpk, bfh + (size_t)i * 16384, bfl + (size_t)i * 16384,
                       (const u16*)nullptr, (const u16*)nullptr,
                       (const float*)nullptr, y, (u32*)nullptr,
                       (const float*)nullptr, (float*)nullptr, NN, HD, HD);
  };
  auto fused01 = [&](int i){
    hipLaunchKernelGGL((k_mfma_gemm<3>), dim3(GP * 3), dim3(256), 0, stream,
                       xpk, bfh + (size_t)i * 16384, bfl + (size_t)i * 16384,
                       m1h, m1l, b1, y, h1pk,
                       (const float*)nullptr, (float*)nullptr, NN, HD, 0);
  };

  for(int b = 0; b < 2; b++){
    const int* rp = b ? c2ptr : c1ptr;
    const uint2* ecv = b ? ecv2 : ecv1;
    float* score = sc + (size_t)b * NN;
    hipLaunchKernelGGL((k_spmm<true>), dim3(SPB), dim3(256), 0, stream,
                       rp, ecv, w1, xpk);
    if(ded_y){
      // spmm; 8x [fused01(h1,y); mode2; spmm]; mode1; mode2
      for(int i = 0; i < 8; i++){
        fused01(i);
        mode2(score);
        if(i < 7)
          hipLaunchKernelGGL((k_spmm<true>),  dim3(SPB), dim3(256), 0, stream,
                             rp, ecv, y, xpk);
        else
          hipLaunchKernelGGL((k_spmm<false>), dim3(SPB), dim3(256), 0, stream,
                             rp, ecv, y, xpk);
      }
      mode1();
      mode2(score);
    } else {
      // r6-proven serial order (y aliases h1pk)
      mode1();
      mode2(score);
      for(int i = 0; i < 8; i++){
        gemm0(i);
        if(i < 7)
          hipLaunchKernelGGL((k_spmm<true>),  dim3(SPB), dim3(256), 0, stream,
                             rp, ecv, y, xpk);
        else
          hipLaunchKernelGGL((k_spmm<false>), dim3(SPB), dim3(256), 0, stream,
                             rp, ecv, y, xpk);
        mode1();
        mode2(score);
      }
    }
  }

  hipLaunchKernelGGL(k_final, dim3(cdiv(NN, 256)), dim3(256), 0, stream, sc, b3, out);
}

// Round 11
// 4203.467 us; speedup vs baseline: 1.0367x; 1.0367x over previous
//
#include <hip/hip_runtime.h>
#include <hip/hip_fp16.h>

#define NN 100000
#define NE 1600000
#define HD 128
#define HD2 256

// binned scatter params
#define NBK 512
#define RPB 196      // rows per bucket; 512*196 = 100352 >= NN
#define CH  4096     // edges per binscatter block
#define CAP 4096     // staging capacity per bucket (17-sigma above mean 3136)

typedef unsigned int u32;
typedef unsigned short u16;
typedef _Float16 half8 __attribute__((ext_vector_type(8)));
typedef float floatx4 __attribute__((ext_vector_type(4)));

static inline int cdiv(int a, int b){ return (a + b - 1) / b; }

// ---- split-fp16 packing: x ~= h + l * 2^-12, l pre-scaled by 4096 ----
__device__ __forceinline__ u32 split_pack(float v){
  __half h;
  if(fabsf(v) < 6.103515625e-05f) h = __ushort_as_half((u16)0);
  else h = __float2half_rn(v);
  float hf = __half2float(h);
  __half l = __float2half_rn((v - hf) * 4096.0f);
  return (u32)__half_as_ushort(h) | ((u32)__half_as_ushort(l) << 16);
}

// ---------------- fused setup: all-weights split + score zero + bucket-cursor init ----
// weight dests are contiguous in workspace: 8x[128*128] + [128*256] + [256*256] u32.
__global__ void k_setup(const float* __restrict__ w0, const float* __restrict__ w1,
                        const float* __restrict__ w2, const float* __restrict__ w3,
                        const float* __restrict__ w4, const float* __restrict__ w5,
                        const float* __restrict__ w6, const float* __restrict__ w7,
                        const float* __restrict__ m1, const float* __restrict__ m2,
                        u32* __restrict__ wbase, float* __restrict__ sc,
                        int* __restrict__ bcur){
  int bid = blockIdx.x;
  if(bid < 896){
    int idx = bid * 256 + threadIdx.x;      // 896*256 = 229376 exact
    const float* W; int K, N, local;
    if(idx < 131072){
      int wi = idx >> 14; local = idx & 16383; K = HD; N = HD;
      W = wi == 0 ? w0 : wi == 1 ? w1 : wi == 2 ? w2 : wi == 3 ? w3 :
          wi == 4 ? w4 : wi == 5 ? w5 : wi == 6 ? w6 : w7;
    } else if(idx < 163840){
      local = idx - 131072; K = HD; N = HD2; W = m1;
    } else {
      local = idx - 163840; K = HD2; N = HD2; W = m2;
    }
    int n = local / K, k = local - n * K;
    wbase[idx] = split_pack(W[(size_t)k * N + n]);
  } else if(bid < 896 + 782){
    int i = (bid - 896) * 256 + threadIdx.x;
    if(i < 2 * NN) sc[i] = 0.f;
  } else {
    int i = (bid - 896 - 782) * 256 + threadIdx.x;
    if(i < 2 * NBK) bcur[i] = (i & (NBK - 1)) * CAP;
  }
}

// pass B: LDS-binned scatter into fixed-capacity bucket staging (burst writes)
__global__ void k_binscatter(const int* __restrict__ r0a, const int* __restrict__ c0a,
                             const float* __restrict__ v0a,
                             const int* __restrict__ r1a, const int* __restrict__ c1a,
                             const float* __restrict__ v1a,
                             int* __restrict__ bcur,
                             u32* __restrict__ sr0, uint2* __restrict__ sv0,
                             u32* __restrict__ sr1, uint2* __restrict__ sv1){
  __shared__ int cnt[NBK];
  __shared__ int bstart[NBK];
  __shared__ int gbase[NBK];
  __shared__ int sh[256];
  __shared__ u32 srow[CH];
  __shared__ uint2 scvs[CH];
  int z = blockIdx.y;
  const int* rows = z ? r1a : r0a;
  const int* cols = z ? c1a : c0a;
  const float* vals = z ? v1a : v0a;
  int* cur = bcur + z * NBK;
  u32* osr = z ? sr1 : sr0;
  uint2* osv = z ? sv1 : sv0;
  int t = threadIdx.x;
  for(int i = t; i < NBK; i += 256) cnt[i] = 0;
  __syncthreads();
  int e0 = blockIdx.x * CH;
  int total = NE - e0; if(total > CH) total = CH;
  int r_[16], c_[16], b_[16], k_[16]; float v_[16];
  #pragma unroll
  for(int k = 0; k < 16; k++){
    int e = e0 + t + k * 256;
    b_[k] = -1;
    if(e < NE){
      r_[k] = rows[e]; c_[k] = cols[e]; v_[k] = vals[e];
      b_[k] = r_[k] / RPB;
      k_[k] = atomicAdd(&cnt[b_[k]], 1);
    }
  }
  __syncthreads();
  // exclusive scan of cnt[512] with 256 threads (2 elems/thread)
  int v0 = cnt[2 * t], v1 = cnt[2 * t + 1];
  int s2 = v0 + v1;
  sh[t] = s2;
  __syncthreads();
  for(int d = 1; d < 256; d <<= 1){
    int tv = (t >= d) ? sh[t - d] : 0;
    __syncthreads();
    sh[t] += tv;
    __syncthreads();
  }
  int excl = sh[t] - s2;
  bstart[2 * t] = excl;
  bstart[2 * t + 1] = excl + v0;
  __syncthreads();
  // stage into LDS sorted-by-bucket
  #pragma unroll
  for(int k = 0; k < 16; k++){
    if(b_[k] >= 0){
      int slot = bstart[b_[k]] + k_[k];
      srow[slot] = (u32)r_[k];
      scvs[slot] = make_uint2((u32)c_[k], __float_as_uint(v_[k]));
    }
  }
  // reserve staging space per bucket (one atomic per non-empty bucket)
  for(int b = t; b < NBK; b += 256){
    int c = cnt[b];
    if(c > 0) gbase[b] = atomicAdd(&cur[b], c);
  }
  __syncthreads();
  // burst write-out: consecutive i -> same bucket -> contiguous dest
  for(int i = t; i < total; i += 256){
    u32 r = srow[i];
    int b = (int)r / RPB;
    int dest = gbase[b] + (i - bstart[b]);
    osr[dest] = r;
    osv[dest] = scvs[i];
  }
}

// bucket totals -> global bucket bases (exclusive scan over 512), + rowptr[NN]=NE
__global__ void k_bucket_scan(const int* __restrict__ bcur, int* __restrict__ bbase,
                              int* __restrict__ c1ptr, int* __restrict__ c2ptr){
  __shared__ int sh[256];
  int z = blockIdx.x;
  const int* cur = bcur + z * NBK;
  int* bb = bbase + z * NBK;
  int t = threadIdx.x;
  int v0 = cur[2 * t]     - (2 * t) * CAP;
  int v1 = cur[2 * t + 1] - (2 * t + 1) * CAP;
  int s2 = v0 + v1;
  sh[t] = s2;
  __syncthreads();
  for(int d = 1; d < 256; d <<= 1){
    int tv = (t >= d) ? sh[t - d] : 0;
    __syncthreads();
    sh[t] += tv;
    __syncthreads();
  }
  int excl = sh[t] - s2;
  bb[2 * t] = excl;
  bb[2 * t + 1] = excl + v0;
  if(t == 0){
    int* rp = z ? c2ptr : c1ptr;
    rp[NN] = NE;
  }
}

// pass C: per-bucket — LDS row-histogram + local scan -> rowptr, then CSR placement
__global__ void k_bucket_place(const int* __restrict__ bcur, const int* __restrict__ bbase,
                               const u32* __restrict__ sr0, const uint2* __restrict__ sv0,
                               const u32* __restrict__ sr1, const uint2* __restrict__ sv1,
                               int* __restrict__ c1ptr, int* __restrict__ c2ptr,
                               uint2* __restrict__ e0, uint2* __restrict__ e1){
  __shared__ int hist[RPB];
  __shared__ int cur[RPB];
  __shared__ int sh[256];
  __shared__ u32 srows[CAP];
  int z = blockIdx.y;
  int b = blockIdx.x;
  int r0 = b * RPB;
  if(r0 >= NN) return;
  int rend = r0 + RPB; if(rend > NN) rend = NN;
  int nr = rend - r0;
  const u32* sr = z ? sr1 : sr0;
  const uint2* sv = z ? sv1 : sv0;
  int* rp = z ? c2ptr : c1ptr;
  uint2* ecv = z ? e1 : e0;
  int cnt = bcur[z * NBK + b] - b * CAP;
  int base = bbase[z * NBK + b];
  int g = b * CAP;
  int t = threadIdx.x;
  for(int r = t; r < nr; r += 256) hist[r] = 0;
  __syncthreads();
  for(int i = t; i < cnt; i += 256){
    u32 r = sr[g + i];
    srows[i] = r;
    atomicAdd(&hist[(int)r - r0], 1);
  }
  __syncthreads();
  int v = (t < nr) ? hist[t] : 0;
  sh[t] = v;
  __syncthreads();
  for(int d = 1; d < 256; d <<= 1){
    int tv = (t >= d) ? sh[t - d] : 0;
    __syncthreads();
    sh[t] += tv;
    __syncthreads();
  }
  int excl = sh[t] - v;
  if(t < nr){
    rp[r0 + t] = base + excl;
    cur[t] = base + excl;
  }
  __syncthreads();
  for(int i = t; i < cnt; i += 256){
    int r = (int)srows[i] - r0;
    int p = atomicAdd(&cur[r], 1);
    ecv[p] = sv[g + i];
  }
}

// ---------------- SpMM: one wave per node; 2 edges/step via half-waves, float4 gather ----
// 16-edge batch tier (avg degree = 16) keeps 8 gathers in flight per half-wave (MLP).
template<bool NORM>
__global__ void k_spmm(const int* __restrict__ rowptr, const uint2* __restrict__ ecv,
                       const float* __restrict__ X, u32* __restrict__ outpk){
  int node = (blockIdx.x << 2) + (threadIdx.x >> 6);
  int lane = threadIdx.x & 63;
  if(node >= NN) return;
  int h = lane >> 5, s = lane & 31;
  int sb = rowptr[node], e = rowptr[node + 1];
  float ax = 0.f, ay = 0.f, az = 0.f, aw = 0.f;
  int i = sb;
  for(; i + 15 < e; i += 16){
    uint2 ee[8]; float4 xx[8];
    #pragma unroll
    for(int j = 0; j < 8; j++) ee[j] = ecv[i + 2 * j + h];
    #pragma unroll
    for(int j = 0; j < 8; j++) xx[j] = *(const float4*)(X + (size_t)ee[j].x * HD + s * 4);
    #pragma unroll
    for(int j = 0; j < 8; j++){
      float vv = __uint_as_float(ee[j].y);
      ax = fmaf(vv, xx[j].x, ax);
      ay = fmaf(vv, xx[j].y, ay);
      az = fmaf(vv, xx[j].z, az);
      aw = fmaf(vv, xx[j].w, aw);
    }
  }
  for(; i + 7 < e; i += 8){
    uint2 ee[4]; float4 xx[4];
    #pragma unroll
    for(int j = 0; j < 4; j++) ee[j] = ecv[i + 2 * j + h];
    #pragma unroll
    for(int j = 0; j < 4; j++) xx[j] = *(const float4*)(X + (size_t)ee[j].x * HD + s * 4);
    #pragma unroll
    for(int j = 0; j < 4; j++){
      float vv = __uint_as_float(ee[j].y);
      ax = fmaf(vv, xx[j].x, ax);
      ay = fmaf(vv, xx[j].y, ay);
      az = fmaf(vv, xx[j].z, az);
      aw = fmaf(vv, xx[j].w, aw);
    }
  }
  for(; i < e; i += 2){
    int idx = i + h;
    bool ok = idx < e;
    uint2 f = ecv[ok ? idx : i];
    float vv = ok ? __uint_as_float(f.y) : 0.f;
    float4 xv = *(const float4*)(X + (size_t)f.x * HD + s * 4);
    ax = fmaf(vv, xv.x, ax);
    ay = fmaf(vv, xv.y, ay);
    az = fmaf(vv, xv.z, az);
    aw = fmaf(vv, xv.w, aw);
  }
  // combine even/odd halves
  ax += __shfl_xor(ax, 32, 64);
  ay += __shfl_xor(ay, 32, 64);
  az += __shfl_xor(az, 32, 64);
  aw += __shfl_xor(aw, 32, 64);
  ax = fmaxf(ax, 0.f); ay = fmaxf(ay, 0.f);
  az = fmaxf(az, 0.f); aw = fmaxf(aw, 0.f);
  if(NORM){
    float ss = ax * ax + ay * ay + az * az + aw * aw;
    #pragma unroll
    for(int o = 16; o >= 1; o >>= 1) ss += __shfl_xor(ss, o, 64);
    float scale = 1.f / fmaxf(sqrtf(ss), 1e-12f);
    ax *= scale; ay *= scale; az *= scale; aw *= scale;
  }
  if(h == 0){
    uint4 p;
    p.x = split_pack(ax); p.y = split_pack(ay);
    p.z = split_pack(az); p.w = split_pack(aw);
    *(uint4*)(outpk + (size_t)node * HD + s * 4) = p;
  }
}

// ---------------- split-fp16 MFMA GEMM (round-6-proven body, XCD-paired col-tiles) ----
// 1-D grid. Block d -> (row-tile rt, col-tile ct) such that all NYC col-tiles of a
// row-panel land on the SAME XCD (d%8 equal), 8 dispatch slots apart -> the A panel
// is fetched from HBM once and L2-hit by the other col-tile(s).
// A: packed [M][K]; Bt: packed [N][K] (pre-transposed).
// MODE 0: Yout = A@B (fp32). MODE 1: Hout = pack(relu(A@B+bias)).
// MODE 2: score[m] += sum_n relu(A@B+bias)[m][n]*m3[n].
// MODE 3: fused — ct==0: mode0 with Bt0 -> Yout [M][HD];
//                 ct in {1,2}: mode1 col-tile with Bt1 -> Hout [M][HD2].
template<int MODE>
__launch_bounds__(256, 2)
__global__ void k_mfma_gemm(const u32* __restrict__ Apk, const u32* __restrict__ Btpk,
                            const u32* __restrict__ Bt1pk,
                            const float* __restrict__ bias, float* __restrict__ Yout,
                            u32* __restrict__ Hout, const float* __restrict__ m3,
                            float* __restrict__ score, int M, int K, int N){
  __shared__ u16 As_h[128 * 40], As_l[128 * 40];
  __shared__ u16 Bs_h[128 * 40], Bs_l[128 * 40];
  constexpr int NYC = (MODE == 0) ? 1 : ((MODE == 3) ? 3 : 2);
  const int d = blockIdx.x;
  const int grp = d / (8 * NYC);
  const int rem = d - grp * 8 * NYC;
  const int rt = grp * 8 + (rem & 7);
  const int ct = rem >> 3;
  const int nrt = (M + 127) >> 7;
  if(rt >= nrt) return;
  const int tid = threadIdx.x;
  const int lane = tid & 63, wid = tid >> 6;
  const int lm = lane & 15, lg = lane >> 4;
  const int mq = (wid & 1) * 64, nq = (wid >> 1) * 64;
  const int m0 = rt * 128;
  int n0 = ct * 128;
  const u32* Bt = Btpk;
  bool m0path = true;
  if(MODE == 3){
    m0path = (ct == 0);
    if(m0path){ n0 = 0; }
    else      { n0 = (ct - 1) * 128; Bt = Bt1pk; }
  }

  floatx4 accA[4][4], accB[4][4];
  #pragma unroll
  for(int i = 0; i < 4; i++)
    #pragma unroll
    for(int j = 0; j < 4; j++){
      accA[i][j] = (floatx4){0.f, 0.f, 0.f, 0.f};
      accB[i][j] = (floatx4){0.f, 0.f, 0.f, 0.f};
    }

  for(int k0 = 0; k0 < K; k0 += 32){
    uint4 av[4], bv[4];
    #pragma unroll
    for(int j = 0; j < 4; j++){
      int li = tid + j * 256;
      int row = li >> 3, kc = (li & 7) * 4;
      int ar = m0 + row; if(ar >= M) ar = M - 1;
      av[j] = *(const uint4*)(Apk + (size_t)ar * K + k0 + kc);
      bv[j] = *(const uint4*)(Bt + (size_t)(n0 + row) * K + k0 + kc);
    }
    if(k0) __syncthreads();
    #pragma unroll
    for(int j = 0; j < 4; j++){
      int li = tid + j * 256;
      int row = li >> 3, kc = (li & 7) * 4;
      int base = row * 40 + kc;
      ushort4 h, l;
      h.x = (u16)(av[j].x & 0xffff); l.x = (u16)(av[j].x >> 16);
      h.y = (u16)(av[j].y & 0xffff); l.y = (u16)(av[j].y >> 16);
      h.z = (u16)(av[j].z & 0xffff); l.z = (u16)(av[j].z >> 16);
      h.w = (u16)(av[j].w & 0xffff); l.w = (u16)(av[j].w >> 16);
      *(ushort4*)&As_h[base] = h;
      *(ushort4*)&As_l[base] = l;
      h.x = (u16)(bv[j].x & 0xffff); l.x = (u16)(bv[j].x >> 16);
      h.y = (u16)(bv[j].y & 0xffff); l.y = (u16)(bv[j].y >> 16);
      h.z = (u16)(bv[j].z & 0xffff); l.z = (u16)(bv[j].z >> 16);
      h.w = (u16)(bv[j].w & 0xffff); l.w = (u16)(bv[j].w >> 16);
      *(ushort4*)&Bs_h[base] = h;
      *(ushort4*)&Bs_l[base] = l;
    }
    __syncthreads();

    half8 fa_h[4], fa_l[4], fb_h[4], fb_l[4];
    #pragma unroll
    for(int s = 0; s < 4; s++){
      int ra = (mq + s * 16 + lm) * 40 + lg * 8;
      fa_h[s] = *(const half8*)&As_h[ra];
      fa_l[s] = *(const half8*)&As_l[ra];
      int rb = (nq + s * 16 + lm) * 40 + lg * 8;
      fb_h[s] = *(const half8*)&Bs_h[rb];
      fb_l[s] = *(const half8*)&Bs_l[rb];
    }
    #pragma unroll
    for(int i = 0; i < 4; i++)
      #pragma unroll
      for(int j = 0; j < 4; j++){
        accA[i][j] = __builtin_amdgcn_mfma_f32_16x16x32_f16(fa_h[i], fb_h[j], accA[i][j], 0, 0, 0);
        accB[i][j] = __builtin_amdgcn_mfma_f32_16x16x32_f16(fa_h[i], fb_l[j], accB[i][j], 0, 0, 0);
        accB[i][j] = __builtin_amdgcn_mfma_f32_16x16x32_f16(fa_l[i], fb_h[j], accB[i][j], 0, 0, 0);
      }
  }

  const float inv4096 = 1.f / 4096.f;
  if(MODE == 0 || (MODE == 3 && m0path)){
    int ldy = (MODE == 3) ? HD : N;
    #pragma unroll
    for(int i = 0; i < 4; i++)
      #pragma unroll
      for(int r = 0; r < 4; r++){
        int m = m0 + mq + i * 16 + lg * 4 + r;
        if(m < M){
          #pragma unroll
          for(int j = 0; j < 4; j++){
            int c = n0 + nq + j * 16 + lm;
            Yout[(size_t)m * ldy + c] = accA[i][j][r] + accB[i][j][r] * inv4096;
          }
        }
      }
  } else if(MODE == 1 || MODE == 3){
    int ldh = (MODE == 3) ? HD2 : N;
    #pragma unroll
    for(int i = 0; i < 4; i++)
      #pragma unroll
      for(int r = 0; r < 4; r++){
        int m = m0 + mq + i * 16 + lg * 4 + r;
        if(m < M){
          #pragma unroll
          for(int j = 0; j < 4; j++){
            int c = n0 + nq + j * 16 + lm;
            float v = fmaxf(accA[i][j][r] + accB[i][j][r] * inv4096 + bias[c], 0.f);
            Hout[(size_t)m * ldh + c] = split_pack(v);
          }
        }
      }
  } else {
    #pragma unroll
    for(int i = 0; i < 4; i++)
      #pragma unroll
      for(int r = 0; r < 4; r++){
        float s = 0.f;
        #pragma unroll
        for(int j = 0; j < 4; j++){
          int c = n0 + nq + j * 16 + lm;
          float v = fmaxf(accA[i][j][r] + accB[i][j][r] * inv4096 + bias[c], 0.f);
          s = fmaf(v, m3[c], s);
        }
        s += __shfl_xor(s, 1, 64);
        s += __shfl_xor(s, 2, 64);
        s += __shfl_xor(s, 4, 64);
        s += __shfl_xor(s, 8, 64);
        int m = m0 + mq + i * 16 + lg * 4 + r;
        if(lm == 0 && m < M) atomicAdd(&score[m], s);
      }
  }
}

__global__ void k_final(const float* __restrict__ sc, const float* __restrict__ b3,
                        float* __restrict__ out){
  int i = blockIdx.x * 256 + threadIdx.x;
  if(i < NN){
    float b = 9.f * b3[0];
    out[i] = (sc[i] + b) * (sc[NN + i] + b);
  }
}

// ---------------- launcher ----------------
extern "C" void kernel_launch(void* const* d_in, const int* in_sizes, int n_in,
                              void* d_out, int out_size, void* d_ws, size_t ws_size,
                              hipStream_t stream){
  const int*   a1r = (const int*)d_in[0];
  const int*   a1c = (const int*)d_in[1];
  const float* a1v = (const float*)d_in[2];
  const int*   a2r = (const int*)d_in[3];
  const int*   a2c = (const int*)d_in[4];
  const float* a2v = (const float*)d_in[5];
  const float* w1  = (const float*)d_in[6];
  const float* w[8];
  for(int i = 0; i < 8; i++) w[i] = (const float*)d_in[7 + i];
  const float* m1 = (const float*)d_in[15];
  const float* b1 = (const float*)d_in[16];
  const float* m2 = (const float*)d_in[17];
  const float* b2 = (const float*)d_in[18];
  const float* m3 = (const float*)d_in[19];
  const float* b3 = (const float*)d_in[20];
  float* out = (float*)d_out;

  char* base = (char*)d_ws;
  size_t off = 0;
  auto alloc = [&](size_t bytes) -> char* {
    char* r = base + off;
    off += (bytes + 255) & ~(size_t)255;
    return r;
  };
  int*   c1ptr = (int*)  alloc((size_t)(NN + 1) * 4);
  int*   c2ptr = (int*)  alloc((size_t)(NN + 1) * 4);
  uint2* ecv1  = (uint2*)alloc((size_t)NE * 8);
  uint2* ecv2  = (uint2*)alloc((size_t)NE * 8);
  int*   cursor= (int*)  alloc((size_t)2 * NBK * 4);
  int*   bbase = (int*)  alloc((size_t)2 * NBK * 4);
  float* sc    = (float*)alloc((size_t)2 * NN * 4);
  u32*   wtpk[8];
  for(int i = 0; i < 8; i++) wtpk[i] = (u32*)alloc((size_t)HD * HD * 4);
  u32*   m1tpk = (u32*)alloc((size_t)HD2 * HD * 4);
  u32*   m2tpk = (u32*)alloc((size_t)HD2 * HD2 * 4);
  u32*   xpk   = (u32*)alloc((size_t)NN * HD * 4);
  u32*   h1pk  = (u32*)alloc((size_t)NN * HD2 * 4);
  // fused01 tier needs dedicated y (fp32 [NN][HD]); else alias h1pk and run r6 schedule
  size_t need_ded = off + (((size_t)NN * HD * 4 + 255) & ~(size_t)255);
  bool ded_y = (ws_size >= need_ded);
  float* y = ded_y ? (float*)alloc((size_t)NN * HD * 4) : (float*)h1pk;

  // binned-scatter staging aliases h1pk (dead during CSR build): 50.3MB < 102.4MB
  const size_t SZ = (size_t)NBK * CAP;
  char* hb = (char*)h1pk;
  uint2* sv1 = (uint2*)hb;
  u32*   sr1 = (u32*)(hb + SZ * 8);
  uint2* sv2 = (uint2*)(hb + SZ * 12);
  u32*   sr2 = (u32*)(hb + SZ * 20);

  // ---- fused setup (weight split + sc zero + bucket cursor init), then CSR build ----
  hipLaunchKernelGGL(k_setup, dim3(896 + 782 + 4), dim3(256), 0, stream,
                     w[0], w[1], w[2], w[3], w[4], w[5], w[6], w[7], m1, m2,
                     wtpk[0], sc, cursor);
  hipLaunchKernelGGL(k_binscatter, dim3(cdiv(NE, CH), 2), dim3(256), 0, stream,
                     a1r, a1c, a1v, a2r, a2c, a2v, cursor, sr1, sv1, sr2, sv2);
  hipLaunchKernelGGL(k_bucket_scan, dim3(2), dim3(256), 0, stream, cursor, bbase, c1ptr, c2ptr);
  hipLaunchKernelGGL(k_bucket_place, dim3(NBK, 2), dim3(256), 0, stream,
                     cursor, bbase, sr1, sv1, sr2, sv2, c1ptr, c2ptr, ecv1, ecv2);

  const int NRT = cdiv(NN, 128);          // 782 row tiles
  const int GP  = cdiv(NRT, 8) * 8;       // 784 padded rows
  const int SPB = cdiv(NN, 4);            // 25000 spmm blocks
  auto mode1 = [&](){
    hipLaunchKernelGGL((k_mfma_gemm<1>), dim3(GP * 2), dim3(256), 0, stream,
                       xpk, m1tpk, (const u32*)nullptr, b1, (float*)nullptr, h1pk,
                       (const float*)nullptr, (float*)nullptr, NN, HD, HD2);
  };
  auto mode2 = [&](float* score){
    hipLaunchKernelGGL((k_mfma_gemm<2>), dim3(GP * 2), dim3(256), 0, stream,
                       h1pk, m2tpk, (const u32*)nullptr, b2, (float*)nullptr, (u32*)nullptr,
                       m3, score, NN, HD2, HD2);
  };
  auto gemm0 = [&](int i){
    hipLaunchKernelGGL((k_mfma_gemm<0>), dim3(GP * 1), dim3(256), 0, stream,
                       xpk, wtpk[i], (const u32*)nullptr, (const float*)nullptr, y, (u32*)nullptr,
                       (const float*)nullptr, (float*)nullptr, NN, HD, HD);
  };
  auto fused01 = [&](int i){
    hipLaunchKernelGGL((k_mfma_gemm<3>), dim3(GP * 3), dim3(256), 0, stream,
                       xpk, wtpk[i], m1tpk, b1, y, h1pk,
                       (const float*)nullptr, (float*)nullptr, NN, HD, 0);
  };

  for(int b = 0; b < 2; b++){
    const int* rp = b ? c2ptr : c1ptr;
    const uint2* ecv = b ? ecv2 : ecv1;
    float* score = sc + (size_t)b * NN;
    hipLaunchKernelGGL((k_spmm<true>), dim3(SPB), dim3(256), 0, stream,
                       rp, ecv, w1, xpk);
    if(ded_y){
      // spmm; 8x [fused01(h1,y); mode2; spmm]; mode1; mode2
      for(int i = 0; i < 8; i++){
        fused01(i);
        mode2(score);
        if(i < 7)
          hipLaunchKernelGGL((k_spmm<true>),  dim3(SPB), dim3(256), 0, stream,
                             rp, ecv, y, xpk);
        else
          hipLaunchKernelGGL((k_spmm<false>), dim3(SPB), dim3(256), 0, stream,
                             rp, ecv, y, xpk);
      }
      mode1();
      mode2(score);
    } else {
      // r6-proven serial order (y aliases h1pk)
      mode1();
      mode2(score);
      for(int i = 0; i < 8; i++){
        gemm0(i);
        if(i < 7)
          hipLaunchKernelGGL((k_spmm<true>),  dim3(SPB), dim3(256), 0, stream,
                             rp, ecv, y, xpk);
        else
          hipLaunchKernelGGL((k_spmm<false>), dim3(SPB), dim3(256), 0, stream,
                             rp, ecv, y, xpk);
        mode1();
        mode2(score);
      }
    }
  }

  hipLaunchKernelGGL(k_final, dim3(cdiv(NN, 256)), dim3(256), 0, stream, sc, b3, out);
}

// Round 12
// 4196.593 us; speedup vs baseline: 1.0384x; 1.0016x over previous
//
#include <hip/hip_runtime.h>
#include <hip/hip_fp16.h>

#define NN 100000
#define NE 1600000
#define HD 128
#define HD2 256

// binned scatter params
#define NBK 512
#define RPB 196      // rows per bucket; 512*196 = 100352 >= NN
#define CH  4096     // edges per binscatter block
#define CAP 4096     // staging capacity per bucket (17-sigma above mean 3136)

typedef unsigned int u32;
typedef unsigned short u16;
typedef _Float16 half8 __attribute__((ext_vector_type(8)));
typedef float floatx4 __attribute__((ext_vector_type(4)));

static inline int cdiv(int a, int b){ return (a + b - 1) / b; }

// ---- split-fp16 packing: x ~= h + l * 2^-12, l pre-scaled by 4096 ----
__device__ __forceinline__ u32 split_pack(float v){
  __half h;
  if(fabsf(v) < 6.103515625e-05f) h = __ushort_as_half((u16)0);
  else h = __float2half_rn(v);
  float hf = __half2float(h);
  __half l = __float2half_rn((v - hf) * 4096.0f);
  return (u32)__half_as_ushort(h) | ((u32)__half_as_ushort(l) << 16);
}

// ---------------- fused setup: all-weights split + score zero + bucket-cursor init ----
__global__ void k_setup(const float* __restrict__ w0, const float* __restrict__ w1,
                        const float* __restrict__ w2, const float* __restrict__ w3,
                        const float* __restrict__ w4, const float* __restrict__ w5,
                        const float* __restrict__ w6, const float* __restrict__ w7,
                        const float* __restrict__ m1, const float* __restrict__ m2,
                        u32* __restrict__ wbase, float* __restrict__ sc,
                        int* __restrict__ bcur){
  int bid = blockIdx.x;
  if(bid < 896){
    int idx = bid * 256 + threadIdx.x;      // 896*256 = 229376 exact
    const float* W; int K, N, local;
    if(idx < 131072){
      int wi = idx >> 14; local = idx & 16383; K = HD; N = HD;
      W = wi == 0 ? w0 : wi == 1 ? w1 : wi == 2 ? w2 : wi == 3 ? w3 :
          wi == 4 ? w4 : wi == 5 ? w5 : wi == 6 ? w6 : w7;
    } else if(idx < 163840){
      local = idx - 131072; K = HD; N = HD2; W = m1;
    } else {
      local = idx - 163840; K = HD2; N = HD2; W = m2;
    }
    int n = local / K, k = local - n * K;
    wbase[idx] = split_pack(W[(size_t)k * N + n]);
  } else if(bid < 896 + 782){
    int i = (bid - 896) * 256 + threadIdx.x;
    if(i < 2 * NN) sc[i] = 0.f;
  } else {
    int i = (bid - 896 - 782) * 256 + threadIdx.x;
    if(i < 2 * NBK) bcur[i] = (i & (NBK - 1)) * CAP;
  }
}

// pass B: LDS-binned scatter into fixed-capacity bucket staging (burst writes)
__global__ void k_binscatter(const int* __restrict__ r0a, const int* __restrict__ c0a,
                             const float* __restrict__ v0a,
                             const int* __restrict__ r1a, const int* __restrict__ c1a,
                             const float* __restrict__ v1a,
                             int* __restrict__ bcur,
                             u32* __restrict__ sr0, uint2* __restrict__ sv0,
                             u32* __restrict__ sr1, uint2* __restrict__ sv1){
  __shared__ int cnt[NBK];
  __shared__ int bstart[NBK];
  __shared__ int gbase[NBK];
  __shared__ int sh[256];
  __shared__ u32 srow[CH];
  __shared__ uint2 scvs[CH];
  int z = blockIdx.y;
  const int* rows = z ? r1a : r0a;
  const int* cols = z ? c1a : c0a;
  const float* vals = z ? v1a : v0a;
  int* cur = bcur + z * NBK;
  u32* osr = z ? sr1 : sr0;
  uint2* osv = z ? sv1 : sv0;
  int t = threadIdx.x;
  for(int i = t; i < NBK; i += 256) cnt[i] = 0;
  __syncthreads();
  int e0 = blockIdx.x * CH;
  int total = NE - e0; if(total > CH) total = CH;
  int r_[16], c_[16], b_[16], k_[16]; float v_[16];
  #pragma unroll
  for(int k = 0; k < 16; k++){
    int e = e0 + t + k * 256;
    b_[k] = -1;
    if(e < NE){
      r_[k] = rows[e]; c_[k] = cols[e]; v_[k] = vals[e];
      b_[k] = r_[k] / RPB;
      k_[k] = atomicAdd(&cnt[b_[k]], 1);
    }
  }
  __syncthreads();
  int v0 = cnt[2 * t], v1 = cnt[2 * t + 1];
  int s2 = v0 + v1;
  sh[t] = s2;
  __syncthreads();
  for(int d = 1; d < 256; d <<= 1){
    int tv = (t >= d) ? sh[t - d] : 0;
    __syncthreads();
    sh[t] += tv;
    __syncthreads();
  }
  int excl = sh[t] - s2;
  bstart[2 * t] = excl;
  bstart[2 * t + 1] = excl + v0;
  __syncthreads();
  #pragma unroll
  for(int k = 0; k < 16; k++){
    if(b_[k] >= 0){
      int slot = bstart[b_[k]] + k_[k];
      srow[slot] = (u32)r_[k];
      scvs[slot] = make_uint2((u32)c_[k], __float_as_uint(v_[k]));
    }
  }
  for(int b = t; b < NBK; b += 256){
    int c = cnt[b];
    if(c > 0) gbase[b] = atomicAdd(&cur[b], c);
  }
  __syncthreads();
  for(int i = t; i < total; i += 256){
    u32 r = srow[i];
    int b = (int)r / RPB;
    int dest = gbase[b] + (i - bstart[b]);
    osr[dest] = r;
    osv[dest] = scvs[i];
  }
}

// bucket totals -> global bucket bases (exclusive scan over 512), + rowptr[NN]=NE
__global__ void k_bucket_scan(const int* __restrict__ bcur, int* __restrict__ bbase,
                              int* __restrict__ c1ptr, int* __restrict__ c2ptr){
  __shared__ int sh[256];
  int z = blockIdx.x;
  const int* cur = bcur + z * NBK;
  int* bb = bbase + z * NBK;
  int t = threadIdx.x;
  int v0 = cur[2 * t]     - (2 * t) * CAP;
  int v1 = cur[2 * t + 1] - (2 * t + 1) * CAP;
  int s2 = v0 + v1;
  sh[t] = s2;
  __syncthreads();
  for(int d = 1; d < 256; d <<= 1){
    int tv = (t >= d) ? sh[t - d] : 0;
    __syncthreads();
    sh[t] += tv;
    __syncthreads();
  }
  int excl = sh[t] - s2;
  bb[2 * t] = excl;
  bb[2 * t + 1] = excl + v0;
  if(t == 0){
    int* rp = z ? c2ptr : c1ptr;
    rp[NN] = NE;
  }
}

// pass C: per-bucket — LDS row-histogram + local scan -> rowptr, then CSR placement
__global__ void k_bucket_place(const int* __restrict__ bcur, const int* __restrict__ bbase,
                               const u32* __restrict__ sr0, const uint2* __restrict__ sv0,
                               const u32* __restrict__ sr1, const uint2* __restrict__ sv1,
                               int* __restrict__ c1ptr, int* __restrict__ c2ptr,
                               uint2* __restrict__ e0, uint2* __restrict__ e1){
  __shared__ int hist[RPB];
  __shared__ int cur[RPB];
  __shared__ int sh[256];
  __shared__ u32 srows[CAP];
  int z = blockIdx.y;
  int b = blockIdx.x;
  int r0 = b * RPB;
  if(r0 >= NN) return;
  int rend = r0 + RPB; if(rend > NN) rend = NN;
  int nr = rend - r0;
  const u32* sr = z ? sr1 : sr0;
  const uint2* sv = z ? sv1 : sv0;
  int* rp = z ? c2ptr : c1ptr;
  uint2* ecv = z ? e1 : e0;
  int cnt = bcur[z * NBK + b] - b * CAP;
  int base = bbase[z * NBK + b];
  int g = b * CAP;
  int t = threadIdx.x;
  for(int r = t; r < nr; r += 256) hist[r] = 0;
  __syncthreads();
  for(int i = t; i < cnt; i += 256){
    u32 r = sr[g + i];
    srows[i] = r;
    atomicAdd(&hist[(int)r - r0], 1);
  }
  __syncthreads();
  int v = (t < nr) ? hist[t] : 0;
  sh[t] = v;
  __syncthreads();
  for(int d = 1; d < 256; d <<= 1){
    int tv = (t >= d) ? sh[t - d] : 0;
    __syncthreads();
    sh[t] += tv;
    __syncthreads();
  }
  int excl = sh[t] - v;
  if(t < nr){
    rp[r0 + t] = base + excl;
    cur[t] = base + excl;
  }
  __syncthreads();
  for(int i = t; i < cnt; i += 256){
    int r = (int)srows[i] - r0;
    int p = atomicAdd(&cur[r], 1);
    ecv[p] = sv[g + i];
  }
}

// ---------------- SpMM: one wave per node; 2 edges/step via half-waves, float4 gather ----
template<bool NORM>
__global__ void k_spmm(const int* __restrict__ rowptr, const uint2* __restrict__ ecv,
                       const float* __restrict__ X, u32* __restrict__ outpk){
  int node = (blockIdx.x << 2) + (threadIdx.x >> 6);
  int lane = threadIdx.x & 63;
  if(node >= NN) return;
  int h = lane >> 5, s = lane & 31;
  int sb = rowptr[node], e = rowptr[node + 1];
  float ax = 0.f, ay = 0.f, az = 0.f, aw = 0.f;
  int i = sb;
  for(; i + 15 < e; i += 16){
    uint2 ee[8]; float4 xx[8];
    #pragma unroll
    for(int j = 0; j < 8; j++) ee[j] = ecv[i + 2 * j + h];
    #pragma unroll
    for(int j = 0; j < 8; j++) xx[j] = *(const float4*)(X + (size_t)ee[j].x * HD + s * 4);
    #pragma unroll
    for(int j = 0; j < 8; j++){
      float vv = __uint_as_float(ee[j].y);
      ax = fmaf(vv, xx[j].x, ax);
      ay = fmaf(vv, xx[j].y, ay);
      az = fmaf(vv, xx[j].z, az);
      aw = fmaf(vv, xx[j].w, aw);
    }
  }
  for(; i + 7 < e; i += 8){
    uint2 ee[4]; float4 xx[4];
    #pragma unroll
    for(int j = 0; j < 4; j++) ee[j] = ecv[i + 2 * j + h];
    #pragma unroll
    for(int j = 0; j < 4; j++) xx[j] = *(const float4*)(X + (size_t)ee[j].x * HD + s * 4);
    #pragma unroll
    for(int j = 0; j < 4; j++){
      float vv = __uint_as_float(ee[j].y);
      ax = fmaf(vv, xx[j].x, ax);
      ay = fmaf(vv, xx[j].y, ay);
      az = fmaf(vv, xx[j].z, az);
      aw = fmaf(vv, xx[j].w, aw);
    }
  }
  for(; i < e; i += 2){
    int idx = i + h;
    bool ok = idx < e;
    uint2 f = ecv[ok ? idx : i];
    float vv = ok ? __uint_as_float(f.y) : 0.f;
    float4 xv = *(const float4*)(X + (size_t)f.x * HD + s * 4);
    ax = fmaf(vv, xv.x, ax);
    ay = fmaf(vv, xv.y, ay);
    az = fmaf(vv, xv.z, az);
    aw = fmaf(vv, xv.w, aw);
  }
  ax += __shfl_xor(ax, 32, 64);
  ay += __shfl_xor(ay, 32, 64);
  az += __shfl_xor(az, 32, 64);
  aw += __shfl_xor(aw, 32, 64);
  ax = fmaxf(ax, 0.f); ay = fmaxf(ay, 0.f);
  az = fmaxf(az, 0.f); aw = fmaxf(aw, 0.f);
  if(NORM){
    float ss = ax * ax + ay * ay + az * az + aw * aw;
    #pragma unroll
    for(int o = 16; o >= 1; o >>= 1) ss += __shfl_xor(ss, o, 64);
    float scale = 1.f / fmaxf(sqrtf(ss), 1e-12f);
    ax *= scale; ay *= scale; az *= scale; aw *= scale;
  }
  if(h == 0){
    uint4 p;
    p.x = split_pack(ax); p.y = split_pack(ay);
    p.z = split_pack(az); p.w = split_pack(aw);
    *(uint4*)(outpk + (size_t)node * HD + s * 4) = p;
  }
}

// ---------------- split-fp16 MFMA GEMM body (round-6-proven, XCD-paired col-tiles) ----
// MODE 0: Yout = A@B (fp32). MODE 1: Hout = pack(relu(A@B+bias)).
// MODE 2: score[m] += sum_n relu(A@B+bias)[m][n]*m3[n].
// MODE 3: fused — ct==0: mode0 -> Yout [M][HD]; ct in {1,2}: mode1 with Bt1 -> Hout.
template<int MODE>
__device__ __forceinline__ void dev_gemm(int d,
                            const u32* __restrict__ Apk, const u32* __restrict__ Btpk,
                            const u32* __restrict__ Bt1pk,
                            const float* __restrict__ bias, float* __restrict__ Yout,
                            u32* __restrict__ Hout, const float* __restrict__ m3,
                            float* __restrict__ score, int M, int K, int N,
                            u16* As_h, u16* As_l, u16* Bs_h, u16* Bs_l){
  constexpr int NYC = (MODE == 0) ? 1 : ((MODE == 3) ? 3 : 2);
  const int grp = d / (8 * NYC);
  const int rem = d - grp * 8 * NYC;
  const int rt = grp * 8 + (rem & 7);
  const int ct = rem >> 3;
  const int nrt = (M + 127) >> 7;
  if(rt >= nrt) return;
  const int tid = threadIdx.x;
  const int lane = tid & 63, wid = tid >> 6;
  const int lm = lane & 15, lg = lane >> 4;
  const int mq = (wid & 1) * 64, nq = (wid >> 1) * 64;
  const int m0 = rt * 128;
  int n0 = ct * 128;
  const u32* Bt = Btpk;
  bool m0path = true;
  if(MODE == 3){
    m0path = (ct == 0);
    if(m0path){ n0 = 0; }
    else      { n0 = (ct - 1) * 128; Bt = Bt1pk; }
  }

  floatx4 accA[4][4], accB[4][4];
  #pragma unroll
  for(int i = 0; i < 4; i++)
    #pragma unroll
    for(int j = 0; j < 4; j++){
      accA[i][j] = (floatx4){0.f, 0.f, 0.f, 0.f};
      accB[i][j] = (floatx4){0.f, 0.f, 0.f, 0.f};
    }

  for(int k0 = 0; k0 < K; k0 += 32){
    uint4 av[4], bv[4];
    #pragma unroll
    for(int j = 0; j < 4; j++){
      int li = tid + j * 256;
      int row = li >> 3, kc = (li & 7) * 4;
      int ar = m0 + row; if(ar >= M) ar = M - 1;
      av[j] = *(const uint4*)(Apk + (size_t)ar * K + k0 + kc);
      bv[j] = *(const uint4*)(Bt + (size_t)(n0 + row) * K + k0 + kc);
    }
    if(k0) __syncthreads();
    #pragma unroll
    for(int j = 0; j < 4; j++){
      int li = tid + j * 256;
      int row = li >> 3, kc = (li & 7) * 4;
      int base = row * 40 + kc;
      ushort4 h, l;
      h.x = (u16)(av[j].x & 0xffff); l.x = (u16)(av[j].x >> 16);
      h.y = (u16)(av[j].y & 0xffff); l.y = (u16)(av[j].y >> 16);
      h.z = (u16)(av[j].z & 0xffff); l.z = (u16)(av[j].z >> 16);
      h.w = (u16)(av[j].w & 0xffff); l.w = (u16)(av[j].w >> 16);
      *(ushort4*)&As_h[base] = h;
      *(ushort4*)&As_l[base] = l;
      h.x = (u16)(bv[j].x & 0xffff); l.x = (u16)(bv[j].x >> 16);
      h.y = (u16)(bv[j].y & 0xffff); l.y = (u16)(bv[j].y >> 16);
      h.z = (u16)(bv[j].z & 0xffff); l.z = (u16)(bv[j].z >> 16);
      h.w = (u16)(bv[j].w & 0xffff); l.w = (u16)(bv[j].w >> 16);
      *(ushort4*)&Bs_h[base] = h;
      *(ushort4*)&Bs_l[base] = l;
    }
    __syncthreads();

    half8 fa_h[4], fa_l[4], fb_h[4], fb_l[4];
    #pragma unroll
    for(int s = 0; s < 4; s++){
      int ra = (mq + s * 16 + lm) * 40 + lg * 8;
      fa_h[s] = *(const half8*)&As_h[ra];
      fa_l[s] = *(const half8*)&As_l[ra];
      int rb = (nq + s * 16 + lm) * 40 + lg * 8;
      fb_h[s] = *(const half8*)&Bs_h[rb];
      fb_l[s] = *(const half8*)&Bs_l[rb];
    }
    #pragma unroll
    for(int i = 0; i < 4; i++)
      #pragma unroll
      for(int j = 0; j < 4; j++){
        accA[i][j] = __builtin_amdgcn_mfma_f32_16x16x32_f16(fa_h[i], fb_h[j], accA[i][j], 0, 0, 0);
        accB[i][j] = __builtin_amdgcn_mfma_f32_16x16x32_f16(fa_h[i], fb_l[j], accB[i][j], 0, 0, 0);
        accB[i][j] = __builtin_amdgcn_mfma_f32_16x16x32_f16(fa_l[i], fb_h[j], accB[i][j], 0, 0, 0);
      }
  }

  const float inv4096 = 1.f / 4096.f;
  if(MODE == 0 || (MODE == 3 && m0path)){
    int ldy = (MODE == 3) ? HD : N;
    #pragma unroll
    for(int i = 0; i < 4; i++)
      #pragma unroll
      for(int r = 0; r < 4; r++){
        int m = m0 + mq + i * 16 + lg * 4 + r;
        if(m < M){
          #pragma unroll
          for(int j = 0; j < 4; j++){
            int c = n0 + nq + j * 16 + lm;
            Yout[(size_t)m * ldy + c] = accA[i][j][r] + accB[i][j][r] * inv4096;
          }
        }
      }
  } else if(MODE == 1 || MODE == 3){
    int ldh = (MODE == 3) ? HD2 : N;
    #pragma unroll
    for(int i = 0; i < 4; i++)
      #pragma unroll
      for(int r = 0; r < 4; r++){
        int m = m0 + mq + i * 16 + lg * 4 + r;
        if(m < M){
          #pragma unroll
          for(int j = 0; j < 4; j++){
            int c = n0 + nq + j * 16 + lm;
            float v = fmaxf(accA[i][j][r] + accB[i][j][r] * inv4096 + bias[c], 0.f);
            Hout[(size_t)m * ldh + c] = split_pack(v);
          }
        }
      }
  } else {
    #pragma unroll
    for(int i = 0; i < 4; i++)
      #pragma unroll
      for(int r = 0; r < 4; r++){
        float s = 0.f;
        #pragma unroll
        for(int j = 0; j < 4; j++){
          int c = n0 + nq + j * 16 + lm;
          float v = fmaxf(accA[i][j][r] + accB[i][j][r] * inv4096 + bias[c], 0.f);
          s = fmaf(v, m3[c], s);
        }
        s += __shfl_xor(s, 1, 64);
        s += __shfl_xor(s, 2, 64);
        s += __shfl_xor(s, 4, 64);
        s += __shfl_xor(s, 8, 64);
        int m = m0 + mq + i * 16 + lg * 4 + r;
        if(lm == 0 && m < M) atomicAdd(&score[m], s);
      }
  }
}

template<int MODE>
__launch_bounds__(256, 2)
__global__ void k_mfma_gemm(const u32* __restrict__ Apk, const u32* __restrict__ Btpk,
                            const u32* __restrict__ Bt1pk,
                            const float* __restrict__ bias, float* __restrict__ Yout,
                            u32* __restrict__ Hout, const float* __restrict__ m3,
                            float* __restrict__ score, int M, int K, int N){
  __shared__ u16 As_h[128 * 40], As_l[128 * 40];
  __shared__ u16 Bs_h[128 * 40], Bs_l[128 * 40];
  dev_gemm<MODE>(blockIdx.x, Apk, Btpk, Bt1pk, bias, Yout, Hout, m3, score,
                 M, K, N, As_h, As_l, Bs_h, Bs_l);
}

// ---- dual GEMM co-dispatch: blocks [0,GA) run mode MA; [GA,GA+GB) run mode MB ----
// Both branches are the same resource class (40KB LDS, ~104 VGPR, 2 blocks/CU),
// so co-residency costs nothing (unlike r6's heterogeneous pairing).
template<int MA, int MB>
__launch_bounds__(256, 2)
__global__ void k_dual(const u32* __restrict__ Aa, const u32* __restrict__ Ba,
                       const u32* __restrict__ B1a, const float* __restrict__ biasa,
                       float* __restrict__ Ya, u32* __restrict__ Ha,
                       int Ma, int Ka, int Na,
                       const u32* __restrict__ Ab, const u32* __restrict__ Bb,
                       const float* __restrict__ biasb, const float* __restrict__ m3,
                       float* __restrict__ score, int Mb, int Kb, int Nb, int GA){
  __shared__ u16 As_h[128 * 40], As_l[128 * 40];
  __shared__ u16 Bs_h[128 * 40], Bs_l[128 * 40];
  if((int)blockIdx.x < GA)
    dev_gemm<MA>(blockIdx.x, Aa, Ba, B1a, biasa, Ya, Ha,
                 (const float*)nullptr, (float*)nullptr, Ma, Ka, Na,
                 As_h, As_l, Bs_h, Bs_l);
  else
    dev_gemm<MB>((int)blockIdx.x - GA, Ab, Bb, (const u32*)nullptr, biasb,
                 (float*)nullptr, (u32*)nullptr, m3, score, Mb, Kb, Nb,
                 As_h, As_l, Bs_h, Bs_l);
}

__global__ void k_final(const float* __restrict__ sc, const float* __restrict__ b3,
                        float* __restrict__ out){
  int i = blockIdx.x * 256 + threadIdx.x;
  if(i < NN){
    float b = 9.f * b3[0];
    out[i] = (sc[i] + b) * (sc[NN + i] + b);
  }
}

// ---------------- launcher ----------------
extern "C" void kernel_launch(void* const* d_in, const int* in_sizes, int n_in,
                              void* d_out, int out_size, void* d_ws, size_t ws_size,
                              hipStream_t stream){
  const int*   a1r = (const int*)d_in[0];
  const int*   a1c = (const int*)d_in[1];
  const float* a1v = (const float*)d_in[2];
  const int*   a2r = (const int*)d_in[3];
  const int*   a2c = (const int*)d_in[4];
  const float* a2v = (const float*)d_in[5];
  const float* w1  = (const float*)d_in[6];
  const float* w[8];
  for(int i = 0; i < 8; i++) w[i] = (const float*)d_in[7 + i];
  const float* m1 = (const float*)d_in[15];
  const float* b1 = (const float*)d_in[16];
  const float* m2 = (const float*)d_in[17];
  const float* b2 = (const float*)d_in[18];
  const float* m3 = (const float*)d_in[19];
  const float* b3 = (const float*)d_in[20];
  float* out = (float*)d_out;

  char* base = (char*)d_ws;
  size_t off = 0;
  auto alloc = [&](size_t bytes) -> char* {
    char* r = base + off;
    off += (bytes + 255) & ~(size_t)255;
    return r;
  };
  int*   c1ptr = (int*)  alloc((size_t)(NN + 1) * 4);
  int*   c2ptr = (int*)  alloc((size_t)(NN + 1) * 4);
  uint2* ecv1  = (uint2*)alloc((size_t)NE * 8);
  uint2* ecv2  = (uint2*)alloc((size_t)NE * 8);
  int*   cursor= (int*)  alloc((size_t)2 * NBK * 4);
  int*   bbase = (int*)  alloc((size_t)2 * NBK * 4);
  float* sc    = (float*)alloc((size_t)2 * NN * 4);
  u32*   wtpk[8];
  for(int i = 0; i < 8; i++) wtpk[i] = (u32*)alloc((size_t)HD * HD * 4);
  u32*   m1tpk = (u32*)alloc((size_t)HD2 * HD * 4);
  u32*   m2tpk = (u32*)alloc((size_t)HD2 * HD2 * 4);
  u32*   xpk   = (u32*)alloc((size_t)NN * HD * 4);
  u32*   h1pk  = (u32*)alloc((size_t)NN * HD2 * 4);
  // tier 1: dedicated y (fp32 [NN][HD])
  size_t need_ded = off + (((size_t)NN * HD * 4 + 255) & ~(size_t)255);
  bool ded_y = (ws_size >= need_ded);
  float* y = ded_y ? (float*)alloc((size_t)NN * HD * 4) : (float*)h1pk;
  // tier 2: double-buffered H for dual GEMM co-dispatch
  size_t need_ded2 = off + (((size_t)NN * HD2 * 4 + 255) & ~(size_t)255);
  bool ded2 = ded_y && (ws_size >= need_ded2);
  u32* h2pk = ded2 ? (u32*)alloc((size_t)NN * HD2 * 4) : h1pk;
  u32* hbuf[2] = { h1pk, h2pk };

  // binned-scatter staging aliases h1pk (dead during CSR build): 50.3MB < 102.4MB
  const size_t SZ = (size_t)NBK * CAP;
  char* hb = (char*)h1pk;
  uint2* sv1 = (uint2*)hb;
  u32*   sr1 = (u32*)(hb + SZ * 8);
  uint2* sv2 = (uint2*)(hb + SZ * 12);
  u32*   sr2 = (u32*)(hb + SZ * 20);

  // ---- fused setup (weight split + sc zero + bucket cursor init), then CSR build ----
  hipLaunchKernelGGL(k_setup, dim3(896 + 782 + 4), dim3(256), 0, stream,
                     w[0], w[1], w[2], w[3], w[4], w[5], w[6], w[7], m1, m2,
                     wtpk[0], sc, cursor);
  hipLaunchKernelGGL(k_binscatter, dim3(cdiv(NE, CH), 2), dim3(256), 0, stream,
                     a1r, a1c, a1v, a2r, a2c, a2v, cursor, sr1, sv1, sr2, sv2);
  hipLaunchKernelGGL(k_bucket_scan, dim3(2), dim3(256), 0, stream, cursor, bbase, c1ptr, c2ptr);
  hipLaunchKernelGGL(k_bucket_place, dim3(NBK, 2), dim3(256), 0, stream,
                     cursor, bbase, sr1, sv1, sr2, sv2, c1ptr, c2ptr, ecv1, ecv2);

  const int NRT = cdiv(NN, 128);          // 782 row tiles
  const int GP  = cdiv(NRT, 8) * 8;       // 784 padded rows
  const int SPB = cdiv(NN, 4);            // 25000 spmm blocks
  auto mode1 = [&](u32* hdst){
    hipLaunchKernelGGL((k_mfma_gemm<1>), dim3(GP * 2), dim3(256), 0, stream,
                       xpk, m1tpk, (const u32*)nullptr, b1, (float*)nullptr, hdst,
                       (const float*)nullptr, (float*)nullptr, NN, HD, HD2);
  };
  auto mode2 = [&](float* score, const u32* hsrc){
    hipLaunchKernelGGL((k_mfma_gemm<2>), dim3(GP * 2), dim3(256), 0, stream,
                       hsrc, m2tpk, (const u32*)nullptr, b2, (float*)nullptr, (u32*)nullptr,
                       m3, score, NN, HD2, HD2);
  };
  auto gemm0 = [&](int i){
    hipLaunchKernelGGL((k_mfma_gemm<0>), dim3(GP * 1), dim3(256), 0, stream,
                       xpk, wtpk[i], (const u32*)nullptr, (const float*)nullptr, y, (u32*)nullptr,
                       (const float*)nullptr, (float*)nullptr, NN, HD, HD);
  };
  auto fused01 = [&](int i, u32* hdst){
    hipLaunchKernelGGL((k_mfma_gemm<3>), dim3(GP * 3), dim3(256), 0, stream,
                       xpk, wtpk[i], m1tpk, b1, y, hdst,
                       (const float*)nullptr, (float*)nullptr, NN, HD, 0);
  };
  // dual: fused01(i)->hdst  ||  mode2(hsrc)->score
  auto dual32 = [&](int i, u32* hdst, const u32* hsrc, float* score){
    hipLaunchKernelGGL((k_dual<3, 2>), dim3(GP * 3 + GP * 2), dim3(256), 0, stream,
                       xpk, wtpk[i], m1tpk, b1, y, hdst, NN, HD, 0,
                       hsrc, m2tpk, b2, m3, score, NN, HD2, HD2, GP * 3);
  };
  // dual: mode1->hdst  ||  mode2(hsrc)->score
  auto dual12 = [&](u32* hdst, const u32* hsrc, float* score){
    hipLaunchKernelGGL((k_dual<1, 2>), dim3(GP * 2 + GP * 2), dim3(256), 0, stream,
                       xpk, m1tpk, (const u32*)nullptr, b1, (float*)nullptr, hdst, NN, HD, HD2,
                       hsrc, m2tpk, b2, m3, score, NN, HD2, HD2, GP * 2);
  };

  for(int b = 0; b < 2; b++){
    const int* rp = b ? c2ptr : c1ptr;
    const uint2* ecv = b ? ecv2 : ecv1;
    float* score = sc + (size_t)b * NN;
    hipLaunchKernelGGL((k_spmm<true>), dim3(SPB), dim3(256), 0, stream,
                       rp, ecv, w1, xpk);
    if(ded2){
      // F(0); S(0); 7x [dual(F(i) || M2(i-1)); S(i)]; dual(mode1 || M2(7)); M2(final)
      fused01(0, hbuf[0]);
      hipLaunchKernelGGL((k_spmm<true>), dim3(SPB), dim3(256), 0, stream,
                         rp, ecv, y, xpk);
      for(int i = 1; i < 8; i++){
        dual32(i, hbuf[i & 1], hbuf[(i - 1) & 1], score);
        if(i < 7)
          hipLaunchKernelGGL((k_spmm<true>),  dim3(SPB), dim3(256), 0, stream,
                             rp, ecv, y, xpk);
        else
          hipLaunchKernelGGL((k_spmm<false>), dim3(SPB), dim3(256), 0, stream,
                             rp, ecv, y, xpk);
      }
      dual12(hbuf[0], hbuf[1], score);   // mode1 -> H0  ||  mode2(H1 from F(7))
      mode2(score, hbuf[0]);             // final mode2 reads mode1's H0
    } else if(ded_y){
      // r11 schedule: spmm; 8x [fused01; mode2; spmm]; mode1; mode2
      for(int i = 0; i < 8; i++){
        fused01(i, h1pk);
        mode2(score, h1pk);
        if(i < 7)
          hipLaunchKernelGGL((k_spmm<true>),  dim3(SPB), dim3(256), 0, stream,
                             rp, ecv, y, xpk);
        else
          hipLaunchKernelGGL((k_spmm<false>), dim3(SPB), dim3(256), 0, stream,
                             rp, ecv, y, xpk);
      }
      mode1(h1pk);
      mode2(score, h1pk);
    } else {
      // r6-proven serial order (y aliases h1pk)
      mode1(h1pk);
      mode2(score, h1pk);
      for(int i = 0; i < 8; i++){
        gemm0(i);
        if(i < 7)
          hipLaunchKernelGGL((k_spmm<true>),  dim3(SPB), dim3(256), 0, stream,
                             rp, ecv, y, xpk);
        else
          hipLaunchKernelGGL((k_spmm<false>), dim3(SPB), dim3(256), 0, stream,
                             rp, ecv, y, xpk);
        mode1(h1pk);
        mode2(score, h1pk);
      }
    }
  }

  hipLaunchKernelGGL(k_final, dim3(cdiv(NN, 256)), dim3(256), 0, stream, sc, b3, out);
}